// Round 8
// baseline (80.697 us; speedup 1.0000x reference)
//
#include <hip/hip_runtime.h>

// RelativePositionAttention collapses algebraically:
//   softmax over w of (Q[t]-K[w]) is Q-independent; sum_w softmax = 1, so
//   out_heads = Vh exactly. => result = values @ M^T with
//   M[i][j] = sum_{h,d} Wp[i*EH + d*H + h] * Wv[(h*E + d)*E + j]  (256x256).
// LayerNorm / Wq / Wk / position_embeddings are dead code.
//
// R8: 2 dispatches (grid.sync=60us R4; single-dispatch full-Wv/block=46us R6).
//  - build: 512 blocks (64 i-groups x 8 j-slices of 32), 2 blocks/CU (32
//    waves/CU), 8 float4 loads/thread, shfl dsub-reduce + LDS kc-reduce.
//  - apply: 256 blocks = (64 r-groups of 8) x (4 e-slices of 64): per-block
//    MT read 64 KB (was 256 KB), padded-LDS kc-reduce, coalesced stores.

constexpr int E  = 256;
constexpr int H  = 4;
constexpr int EH = E * H;   // 1024

// grid 512 x 1024 thr. bx: i0=(bx>>3)*4, j0=(bx&7)*32.
// thread: kc=tid>>6 (wave 0..15), dsub=(lane>>3)&7, jq=lane&7 ->
// owns d in [(kc*8+dsub)*2, +2), all 4 h, j-quad j0+jq*4, 4 i-rows.
__global__ __launch_bounds__(1024) void build_m_kernel(
    const float* __restrict__ Wv, const float* __restrict__ Wp,
    float* __restrict__ MT)
{
    const int tid  = threadIdx.x;
    const int lane = tid & 63;
    const int kc   = tid >> 6;           // 0..15
    const int dsub = lane >> 3;          // 0..7
    const int jq   = lane & 7;           // 0..7
    const int i0   = (blockIdx.x >> 3) * 4;
    const int j0   = (blockIdx.x & 7) * 32;

    __shared__ float sWp[4][EH];         // 16 KB: Wp rows i0..i0+3
    ((float4*)sWp)[tid] = ((const float4*)(Wp + i0 * EH))[tid];  // coalesced
    __syncthreads();

    const int dbase = (kc * 8 + dsub) * 2;
    const int jj    = j0 + jq * 4;

    float4 a0 = {0,0,0,0}, a1 = {0,0,0,0}, a2 = {0,0,0,0}, a3 = {0,0,0,0};
    #pragma unroll
    for (int h = 0; h < H; ++h) {
        const float* __restrict__ p = Wv + (h * E + dbase) * E + jj;
        #pragma unroll
        for (int it = 0; it < 2; ++it) {
            const float4 wv = *(const float4*)(p + it * E);  // 8 indep loads/thread
            const int    k  = (dbase + it) * 4 + h;
            const float w0 = sWp[0][k], w1 = sWp[1][k];      // 2-way LDS = free
            const float w2 = sWp[2][k], w3 = sWp[3][k];
            a0.x += w0*wv.x; a0.y += w0*wv.y; a0.z += w0*wv.z; a0.w += w0*wv.w;
            a1.x += w1*wv.x; a1.y += w1*wv.y; a1.z += w1*wv.z; a1.w += w1*wv.w;
            a2.x += w2*wv.x; a2.y += w2*wv.y; a2.z += w2*wv.z; a2.w += w2*wv.w;
            a3.x += w3*wv.x; a3.y += w3*wv.y; a3.z += w3*wv.z; a3.w += w3*wv.w;
        }
    }

    // butterfly-reduce over dsub (lane^8, ^16, ^32)
    #pragma unroll
    for (int mask = 8; mask < 64; mask <<= 1) {
        a0.x += __shfl_xor(a0.x, mask); a0.y += __shfl_xor(a0.y, mask);
        a0.z += __shfl_xor(a0.z, mask); a0.w += __shfl_xor(a0.w, mask);
        a1.x += __shfl_xor(a1.x, mask); a1.y += __shfl_xor(a1.y, mask);
        a1.z += __shfl_xor(a1.z, mask); a1.w += __shfl_xor(a1.w, mask);
        a2.x += __shfl_xor(a2.x, mask); a2.y += __shfl_xor(a2.y, mask);
        a2.z += __shfl_xor(a2.z, mask); a2.w += __shfl_xor(a2.w, mask);
        a3.x += __shfl_xor(a3.x, mask); a3.y += __shfl_xor(a3.y, mask);
        a3.z += __shfl_xor(a3.z, mask); a3.w += __shfl_xor(a3.w, mask);
    }

    // pad 36: 16B-aligned rows, banks (4*ii + jl) -> conflict-free
    __shared__ float sAcc[16][4][36];    // 9.2 KB
    if (dsub == 0) {                     // lanes 0..7 hold dsub-sums
        *(float4*)&sAcc[kc][0][jq * 4] = a0;
        *(float4*)&sAcc[kc][1][jq * 4] = a1;
        *(float4*)&sAcc[kc][2][jq * 4] = a2;
        *(float4*)&sAcc[kc][3][jq * 4] = a3;
    }
    __syncthreads();

    if (tid < 128) {                     // 4 i x 32 j outputs
        const int ii = tid & 3, jl = tid >> 2;   // jl 0..31
        float v = 0.f;
        #pragma unroll
        for (int c = 0; c < 16; ++c) v += sAcc[c][ii][jl];
        MT[(j0 + jl) * E + i0 + ii] = v;         // 16B segments
    }
}

// out[r,e] = sum_j values[r,j] * MT[j*E + e]
// grid 256: bx -> r0=(bx>>2)*8 (8 rows), ebase=(bx&3)*64 (64 e's).
// thread: kc=tid>>6 -> j-chunk [kc*16,+16); lane: dsub=lane>>4 -> row pair,
// el=lane&15 -> e-quad. Per-block MT traffic 64 KB (3.5x cut vs R7).
__global__ __launch_bounds__(1024) void apply_kernel(
    const float* __restrict__ values, const float* __restrict__ MT,
    float* __restrict__ out)
{
    const int tid  = threadIdx.x;
    const int lane = tid & 63;
    const int kc   = tid >> 6;           // 0..15
    const int dsub = lane >> 4;          // 0..3 -> rows dsub*2, dsub*2+1
    const int el   = lane & 15;          // 0..15
    const int r0   = (blockIdx.x >> 2) * 8;
    const int eb   = (blockIdx.x & 3) * 64;
    const int e0   = eb + el * 4;

    __shared__ float sV[8][257];         // 8.2 KB; pad 257 -> free reads
    {
        const int f0 = tid;              // 2048 elems, 2 per thread, coalesced
        sV[f0 >> 8][f0 & 255] = values[(r0 + (f0 >> 8)) * E + (f0 & 255)];
        const int f1 = tid + 1024;
        sV[f1 >> 8][f1 & 255] = values[(r0 + (f1 >> 8)) * E + (f1 & 255)];
    }
    __syncthreads();

    float4 acc0 = {0,0,0,0}, acc1 = {0,0,0,0};
    #pragma unroll
    for (int jjj = 0; jjj < 16; ++jjj) {
        const int    j = kc * 16 + jjj;
        const float4 m = *(const float4*)&MT[j * E + e0];   // 4x256B segs/instr
        const float v0 = sV[dsub * 2 + 0][j];               // bcast, banks distinct
        const float v1 = sV[dsub * 2 + 1][j];
        acc0.x += v0*m.x; acc0.y += v0*m.y; acc0.z += v0*m.z; acc0.w += v0*m.w;
        acc1.x += v1*m.x; acc1.y += v1*m.y; acc1.z += v1*m.z; acc1.w += v1*m.w;
    }

    // partials: pad 9 -> write banks (16*dsub+9*el+c)%32 <= 2-way = free
    __shared__ float sP[16][4][16][9];   // 36 KB
    #pragma unroll
    for (int c = 0; c < 4; ++c) {
        sP[kc][dsub][el][c]     = (&acc0.x)[c];
        sP[kc][dsub][el][4 + c] = (&acc1.x)[c];
    }
    __syncthreads();

    if (tid < 512) {                     // 8 rows x 64 e outputs
        const int r   = tid >> 6;        // 0..7
        const int e_l = tid & 63;
        const int ds2 = r >> 1, ri = r & 1;
        const int el2 = e_l >> 2, c = e_l & 3;
        float v = 0.f;
        #pragma unroll
        for (int k = 0; k < 16; ++k) v += sP[k][ds2][el2][ri * 4 + c];
        out[(r0 + r) * E + eb + e_l] = v;                   // coalesced 256B
    }
}

extern "C" void kernel_launch(void* const* d_in, const int* in_sizes, int n_in,
                              void* d_out, int out_size, void* d_ws, size_t ws_size,
                              hipStream_t stream) {
    // inputs: 0 pos_emb(unused) 1 values 2 ln_w 3 ln_b 4 Wq 5 Wk 6 Wv 7 Wp
    const float* values = (const float*)d_in[1];
    const float* Wv     = (const float*)d_in[6];
    const float* Wp     = (const float*)d_in[7];
    float*       out    = (float*)d_out;
    float*       MT     = (float*)d_ws;  // E*E floats; fully overwritten by build

    build_m_kernel<<<512, 1024, 0, stream>>>(Wv, Wp, MT);
    apply_kernel<<<256, 1024, 0, stream>>>(values, MT, out);
}